// Round 1
// baseline (328.525 us; speedup 1.0000x reference)
//
#include <hip/hip_runtime.h>
#include <hip/hip_bf16.h>

typedef __attribute__((ext_vector_type(8))) short short8;
typedef __attribute__((ext_vector_type(4))) float floatx4;

__device__ __forceinline__ ushort f2bf(float f) {
    union { __hip_bfloat16 h; ushort u; } cv;
    cv.h = __float2bfloat16(f);
    return cv.u;
}
__device__ __forceinline__ float bf2f(ushort u) {
    union { ushort u; __hip_bfloat16 h; } cv;
    cv.u = u;
    return __bfloat162float(cv.h);
}

// ---------------------------------------------------------------------------
// Kernel 1: cast + transpose weights fp32[R][C] -> bf16[C][R]
// ---------------------------------------------------------------------------
__global__ __launch_bounds__(256) void transpose_cast(const float* __restrict__ in,
                                                      ushort* __restrict__ out,
                                                      int R, int C) {
    __shared__ float tile[32][33];
    int c0 = blockIdx.x * 32, r0 = blockIdx.y * 32;
    int tx = threadIdx.x, ty = threadIdx.y;
    for (int j = 0; j < 32; j += 8)
        tile[ty + j][tx] = in[(size_t)(r0 + ty + j) * C + c0 + tx];
    __syncthreads();
    for (int j = 0; j < 32; j += 8)
        out[(size_t)(c0 + ty + j) * R + r0 + tx] = f2bf(tile[tx][ty + j]);
}

// ---------------------------------------------------------------------------
// Kernel 2: LayerNorm (fp32) -> bf16. One block per row of 1024.
// ---------------------------------------------------------------------------
__global__ __launch_bounds__(256) void ln_kernel(const float* __restrict__ x,
                                                 const float* __restrict__ lw,
                                                 const float* __restrict__ lb,
                                                 ushort* __restrict__ xn) {
    int row = blockIdx.x;
    int tid = threadIdx.x;
    const float4* xr = (const float4*)(x + (size_t)row * 1024);
    float4 v = xr[tid];
    float s = v.x + v.y + v.z + v.w;
    float sq = v.x * v.x + v.y * v.y + v.z * v.z + v.w * v.w;
    for (int off = 32; off; off >>= 1) {
        s += __shfl_xor(s, off);
        sq += __shfl_xor(sq, off);
    }
    __shared__ float ls[4], lq[4];
    int wave = tid >> 6, lane = tid & 63;
    if (lane == 0) { ls[wave] = s; lq[wave] = sq; }
    __syncthreads();
    s = ls[0] + ls[1] + ls[2] + ls[3];
    sq = lq[0] + lq[1] + lq[2] + lq[3];
    float mu = s * (1.0f / 1024.0f);
    float var = sq * (1.0f / 1024.0f) - mu * mu;
    float rs = rsqrtf(var + 1e-5f);
    const float4* wr = (const float4*)lw;
    const float4* br = (const float4*)lb;
    float4 wv = wr[tid], bv = br[tid];
    ushort4 o;
    o.x = f2bf((v.x - mu) * rs * wv.x + bv.x);
    o.y = f2bf((v.y - mu) * rs * wv.y + bv.y);
    o.z = f2bf((v.z - mu) * rs * wv.z + bv.z);
    o.w = f2bf((v.w - mu) * rs * wv.w + bv.w);
    *(ushort4*)&xn[(size_t)row * 1024 + tid * 4] = o;
}

// ---------------------------------------------------------------------------
// Kernel 3: MFMA GEMM  C[M][N] = A[M][K] @ Bt[N][K]^T, bf16 in, OutT out.
// 128x128 block tile, 4 waves (2x2), each 64x64 = 4x4 mfma_16x16x32_bf16.
// LDS row stride 40 elems (80 B: 16B-aligned, only 2-way bank aliasing).
// M,N % 128 == 0, K % 32 == 0 (all shapes here satisfy this).
// ---------------------------------------------------------------------------
template <typename OutT>
__global__ __launch_bounds__(256) void gemm_bt(const ushort* __restrict__ A,
                                               const ushort* __restrict__ Bt,
                                               OutT* __restrict__ C,
                                               int M, int N, int K) {
    __shared__ ushort As[128 * 40];
    __shared__ ushort Bs[128 * 40];
    const int tid = threadIdx.x;
    const int wave = tid >> 6, lane = tid & 63;
    const int quad = lane >> 4, l15 = lane & 15;
    const int wm = (wave >> 1) * 64, wn = (wave & 1) * 64;
    const int bm = blockIdx.y * 128, bn = blockIdx.x * 128;

    const int s0 = tid, s1 = tid + 256;
    const int row0 = s0 >> 2, seg0 = s0 & 3;
    const int row1 = s1 >> 2, seg1 = s1 & 3;

    floatx4 acc[4][4];
    floatx4 z4 = {0.f, 0.f, 0.f, 0.f};
    for (int mi = 0; mi < 4; mi++)
        for (int ni = 0; ni < 4; ni++) acc[mi][ni] = z4;

    const ushort* Ap0 = A + (size_t)(bm + row0) * K + seg0 * 8;
    const ushort* Ap1 = A + (size_t)(bm + row1) * K + seg1 * 8;
    const ushort* Bp0 = Bt + (size_t)(bn + row0) * K + seg0 * 8;
    const ushort* Bp1 = Bt + (size_t)(bn + row1) * K + seg1 * 8;

    for (int k0 = 0; k0 < K; k0 += 32) {
        __syncthreads();
        *(short8*)&As[row0 * 40 + seg0 * 8] = *(const short8*)&Ap0[k0];
        *(short8*)&As[row1 * 40 + seg1 * 8] = *(const short8*)&Ap1[k0];
        *(short8*)&Bs[row0 * 40 + seg0 * 8] = *(const short8*)&Bp0[k0];
        *(short8*)&Bs[row1 * 40 + seg1 * 8] = *(const short8*)&Bp1[k0];
        __syncthreads();
        short8 af[4], bfr[4];
        for (int mi = 0; mi < 4; mi++)
            af[mi] = *(short8*)&As[(wm + mi * 16 + l15) * 40 + quad * 8];
        for (int ni = 0; ni < 4; ni++)
            bfr[ni] = *(short8*)&Bs[(wn + ni * 16 + l15) * 40 + quad * 8];
        for (int mi = 0; mi < 4; mi++)
            for (int ni = 0; ni < 4; ni++)
                acc[mi][ni] = __builtin_amdgcn_mfma_f32_16x16x32_bf16(
                    af[mi], bfr[ni], acc[mi][ni], 0, 0, 0);
    }
    // epilogue: C/D layout col=lane&15, row=quad*4+r
    for (int mi = 0; mi < 4; mi++) {
        for (int ni = 0; ni < 4; ni++) {
            for (int r = 0; r < 4; r++) {
                int row = bm + wm + mi * 16 + quad * 4 + r;
                int col = bn + wn + ni * 16 + l15;
                float val = acc[mi][ni][r];
                if constexpr (sizeof(OutT) == 2)
                    ((ushort*)C)[(size_t)row * N + col] = f2bf(val);
                else
                    ((float*)C)[(size_t)row * N + col] = val;
            }
        }
    }
}

// ---------------------------------------------------------------------------
// Kernel 4: reshape to heads + l2-normalize q,k + transpose v.
// qkv bf16 [4096][3072] -> Q,K [b,h,n,64] bf16 (normalized), Vt [b,h,64,n].
// Grid (n/64, h, b), 256 threads.
// ---------------------------------------------------------------------------
__global__ __launch_bounds__(256) void norm_reshape(const ushort* __restrict__ qkv,
                                                    ushort* __restrict__ Q,
                                                    ushort* __restrict__ K,
                                                    ushort* __restrict__ Vt) {
    int nb = blockIdx.x;   // n-tile of 64
    int h = blockIdx.y;
    int b = blockIdx.z;
    int bh = b * 16 + h;
    int tid = threadIdx.x, wave = tid >> 6, lane = tid & 63;
    __shared__ ushort vt[64][65];  // [d][n_loc]

    // V transpose through LDS
    for (int i = 0; i < 16; i++) {
        int idx = tid + i * 256;
        int n_loc = idx >> 6, d = idx & 63;
        size_t g = ((size_t)(b * 2048 + nb * 64 + n_loc)) * 3072 + 2048 + h * 64 + d;
        vt[d][n_loc] = qkv[g];
    }
    __syncthreads();
    for (int i = 0; i < 16; i++) {
        int idx = tid + i * 256;
        int d = idx >> 6, n_loc = idx & 63;
        Vt[((size_t)bh * 64 + d) * 2048 + nb * 64 + n_loc] = vt[d][n_loc];
    }

    // q,k l2-norm: one wave per row (lane == d), 16 rows per wave
    for (int j = 0; j < 16; j++) {
        int n_loc = wave * 16 + j;
        size_t grow = (size_t)(b * 2048 + nb * 64 + n_loc) * 3072;
        size_t orow = ((size_t)bh * 2048 + nb * 64 + n_loc) * 64;

        float qv = bf2f(qkv[grow + h * 64 + lane]);
        float ss = qv * qv;
        for (int off = 32; off; off >>= 1) ss += __shfl_xor(ss, off);
        float inv = 1.0f / fmaxf(sqrtf(ss), 1e-12f);
        Q[orow + lane] = f2bf(qv * inv);

        float kv = bf2f(qkv[grow + 1024 + h * 64 + lane]);
        ss = kv * kv;
        for (int off = 32; off; off >>= 1) ss += __shfl_xor(ss, off);
        inv = 1.0f / fmaxf(sqrtf(ss), 1e-12f);
        K[orow + lane] = f2bf(kv * inv);
    }
}

// ---------------------------------------------------------------------------
// Kernel 5: causal flash attention. Block = (b,h,q-tile of 64). 4 waves,
// wave w owns q rows [w*16, w*16+16). sim = 8*(q̂·k̂ᵀ), online softmax, PV.
// ---------------------------------------------------------------------------
#define BH_STRIDE (2048 * 64)

__global__ __launch_bounds__(256) void flash_attn(const ushort* __restrict__ Q,
                                                  const ushort* __restrict__ K,
                                                  const ushort* __restrict__ Vt,
                                                  ushort* __restrict__ O) {
    const int qt = blockIdx.x;   // 0..31
    const int h = blockIdx.y;
    const int b = blockIdx.z;
    const int bh = b * 16 + h;
    const int q0 = qt * 64;
    const int tid = threadIdx.x;
    const int wave = tid >> 6, lane = tid & 63;
    const int quad = lane >> 4, l15 = lane & 15;

    __shared__ ushort Qs[64 * 72];
    __shared__ ushort Ks[64 * 72];
    __shared__ ushort Vs[64 * 72];      // Vt tile: [d][kv]
    __shared__ ushort Ps[4][16 * 72];   // per-wave P in A-layout rows

    const ushort* Qg = Q + (size_t)bh * BH_STRIDE + (size_t)q0 * 64;
    const ushort* Kg = K + (size_t)bh * BH_STRIDE;
    const ushort* Vg = Vt + (size_t)bh * BH_STRIDE;

    // stage Q tile (64 rows x 64 d)
    for (int i = 0; i < 2; i++) {
        int s = tid + i * 256;
        int row = s >> 3, seg = s & 7;
        *(short8*)&Qs[row * 72 + seg * 8] = *(const short8*)&Qg[row * 64 + seg * 8];
    }
    __syncthreads();
    short8 qf[2];
    qf[0] = *(short8*)&Qs[(wave * 16 + l15) * 72 + quad * 8];
    qf[1] = *(short8*)&Qs[(wave * 16 + l15) * 72 + 32 + quad * 8];

    float m_st[4], l_st[4];
    floatx4 o_acc[4];
    floatx4 z4 = {0.f, 0.f, 0.f, 0.f};
    for (int r = 0; r < 4; r++) { m_st[r] = -3.0e38f; l_st[r] = 0.f; }
    for (int ni = 0; ni < 4; ni++) o_acc[ni] = z4;

    for (int kt = 0; kt <= qt; kt++) {
        int kv0 = kt * 64;
        __syncthreads();  // prior iter's Ks/Vs reads complete
        for (int i = 0; i < 2; i++) {
            int s = tid + i * 256;
            int row = s >> 3, seg = s & 7;
            *(short8*)&Ks[row * 72 + seg * 8] =
                *(const short8*)&Kg[(size_t)(kv0 + row) * 64 + seg * 8];
            *(short8*)&Vs[row * 72 + seg * 8] =
                *(const short8*)&Vg[(size_t)row * 2048 + kv0 + seg * 8];
        }
        __syncthreads();

        // S = Q K^T (scaled by 8 below)
        floatx4 s_acc[4];
        for (int ni = 0; ni < 4; ni++) s_acc[ni] = z4;
        for (int ni = 0; ni < 4; ni++) {
            short8 bf0 = *(short8*)&Ks[(ni * 16 + l15) * 72 + quad * 8];
            short8 bf1 = *(short8*)&Ks[(ni * 16 + l15) * 72 + 32 + quad * 8];
            s_acc[ni] = __builtin_amdgcn_mfma_f32_16x16x32_bf16(qf[0], bf0, s_acc[ni], 0, 0, 0);
            s_acc[ni] = __builtin_amdgcn_mfma_f32_16x16x32_bf16(qf[1], bf1, s_acc[ni], 0, 0, 0);
        }

        const bool diag = (kt == qt);
        float p[4][4];
        for (int r = 0; r < 4; r++) {
            int grow_loc = wave * 16 + quad * 4 + r;
            float mx = -3.0e38f;
            float sv[4];
            for (int ni = 0; ni < 4; ni++) {
                float sval = s_acc[ni][r] * 8.0f;
                if (diag) {
                    int col_loc = ni * 16 + l15;
                    if (col_loc > grow_loc) sval = -3.0e38f;
                }
                sv[ni] = sval;
                mx = fmaxf(mx, sval);
            }
            for (int off = 1; off < 16; off <<= 1) mx = fmaxf(mx, __shfl_xor(mx, off));
            float m_new = fmaxf(m_st[r], mx);
            float alpha = __expf(m_st[r] - m_new);
            float rs = 0.f;
            for (int ni = 0; ni < 4; ni++) {
                float e = __expf(sv[ni] - m_new);
                p[ni][r] = e;
                rs += e;
            }
            for (int off = 1; off < 16; off <<= 1) rs += __shfl_xor(rs, off);
            l_st[r] = l_st[r] * alpha + rs;
            m_st[r] = m_new;
            for (int ni = 0; ni < 4; ni++) o_acc[ni][r] *= alpha;
        }

        // P -> LDS (C-layout write), reread in A-layout
        for (int ni = 0; ni < 4; ni++)
            for (int r = 0; r < 4; r++)
                Ps[wave][(quad * 4 + r) * 72 + ni * 16 + l15] = f2bf(p[ni][r]);
        short8 pa0 = *(short8*)&Ps[wave][l15 * 72 + quad * 8];
        short8 pa1 = *(short8*)&Ps[wave][l15 * 72 + 32 + quad * 8];
        for (int ni = 0; ni < 4; ni++) {
            short8 v0 = *(short8*)&Vs[(ni * 16 + l15) * 72 + quad * 8];
            short8 v1 = *(short8*)&Vs[(ni * 16 + l15) * 72 + 32 + quad * 8];
            o_acc[ni] = __builtin_amdgcn_mfma_f32_16x16x32_bf16(pa0, v0, o_acc[ni], 0, 0, 0);
            o_acc[ni] = __builtin_amdgcn_mfma_f32_16x16x32_bf16(pa1, v1, o_acc[ni], 0, 0, 0);
        }
    }

    // epilogue: O / l, write as [b, n, h*64 + d] bf16
    for (int r = 0; r < 4; r++) {
        float inv = 1.0f / l_st[r];
        int grow = q0 + wave * 16 + quad * 4 + r;
        size_t rowbase = ((size_t)b * 2048 + grow) * 1024 + h * 64;
        for (int ni = 0; ni < 4; ni++)
            O[rowbase + ni * 16 + l15] = f2bf(o_acc[ni][r] * inv);
    }
}

// ---------------------------------------------------------------------------
extern "C" void kernel_launch(void* const* d_in, const int* in_sizes, int n_in,
                              void* d_out, int out_size, void* d_ws, size_t ws_size,
                              hipStream_t stream) {
    const float* x = (const float*)d_in[0];
    const float* ln_w = (const float*)d_in[1];
    const float* ln_b = (const float*)d_in[2];
    const float* W_qkv = (const float*)d_in[3];
    const float* W_out = (const float*)d_in[4];

    char* w = (char*)d_ws;
    ushort* xn    = (ushort*)(w);                          // 8 MiB
    ushort* WqkvT = (ushort*)(w + (8ull << 20));           // 6 MiB
    ushort* WoutT = (ushort*)(w + (14ull << 20));          // 2 MiB
    ushort* qkv   = (ushort*)(w + (16ull << 20));          // 24 MiB
    ushort* Qn    = (ushort*)(w + (40ull << 20));          // 8 MiB
    ushort* Kn    = (ushort*)(w + (48ull << 20));          // 8 MiB
    ushort* Vt    = (ushort*)(w + (56ull << 20));          // 8 MiB
    ushort* obuf  = (ushort*)(w + (64ull << 20));          // 8 MiB -> 72 MiB total

    transpose_cast<<<dim3(96, 32), dim3(32, 8), 0, stream>>>(W_qkv, WqkvT, 1024, 3072);
    transpose_cast<<<dim3(32, 32), dim3(32, 8), 0, stream>>>(W_out, WoutT, 1024, 1024);
    ln_kernel<<<4096, 256, 0, stream>>>(x, ln_w, ln_b, xn);
    gemm_bt<ushort><<<dim3(24, 32), 256, 0, stream>>>(xn, WqkvT, qkv, 4096, 3072, 1024);
    norm_reshape<<<dim3(32, 16, 2), 256, 0, stream>>>(qkv, Qn, Kn, Vt);
    flash_attn<<<dim3(32, 16, 2), 256, 0, stream>>>(Qn, Kn, Vt, obuf);
    gemm_bt<float><<<dim3(8, 32), 256, 0, stream>>>(obuf, WoutT, (float*)d_out, 4096, 1024, 1024);
}

// Round 2
// 227.497 us; speedup vs baseline: 1.4441x; 1.4441x over previous
//
#include <hip/hip_runtime.h>
#include <hip/hip_bf16.h>

typedef __attribute__((ext_vector_type(8))) short short8;
typedef __attribute__((ext_vector_type(4))) float floatx4;

__device__ __forceinline__ ushort f2bf(float f) {
    union { __hip_bfloat16 h; ushort u; } cv;
    cv.h = __float2bfloat16(f);
    return cv.u;
}
__device__ __forceinline__ float bf2f(ushort u) {
    union { ushort u; __hip_bfloat16 h; } cv;
    cv.u = u;
    return __bfloat162float(cv.h);
}

// ---------------------------------------------------------------------------
// Kernel 1: cast + transpose weights fp32[R][C] -> bf16[C][R]
// ---------------------------------------------------------------------------
__global__ __launch_bounds__(256) void transpose_cast(const float* __restrict__ in,
                                                      ushort* __restrict__ out,
                                                      int R, int C) {
    __shared__ float tile[32][33];
    int c0 = blockIdx.x * 32, r0 = blockIdx.y * 32;
    int tx = threadIdx.x, ty = threadIdx.y;
    for (int j = 0; j < 32; j += 8)
        tile[ty + j][tx] = in[(size_t)(r0 + ty + j) * C + c0 + tx];
    __syncthreads();
    for (int j = 0; j < 32; j += 8)
        out[(size_t)(c0 + ty + j) * R + r0 + tx] = f2bf(tile[tx][ty + j]);
}

// ---------------------------------------------------------------------------
// Kernel 2: LayerNorm (fp32) -> bf16. One block per row of 1024.
// ---------------------------------------------------------------------------
__global__ __launch_bounds__(256) void ln_kernel(const float* __restrict__ x,
                                                 const float* __restrict__ lw,
                                                 const float* __restrict__ lb,
                                                 ushort* __restrict__ xn) {
    int row = blockIdx.x;
    int tid = threadIdx.x;
    const float4* xr = (const float4*)(x + (size_t)row * 1024);
    float4 v = xr[tid];
    float s = v.x + v.y + v.z + v.w;
    float sq = v.x * v.x + v.y * v.y + v.z * v.z + v.w * v.w;
    for (int off = 32; off; off >>= 1) {
        s += __shfl_xor(s, off);
        sq += __shfl_xor(sq, off);
    }
    __shared__ float ls[4], lq[4];
    int wave = tid >> 6, lane = tid & 63;
    if (lane == 0) { ls[wave] = s; lq[wave] = sq; }
    __syncthreads();
    s = ls[0] + ls[1] + ls[2] + ls[3];
    sq = lq[0] + lq[1] + lq[2] + lq[3];
    float mu = s * (1.0f / 1024.0f);
    float var = sq * (1.0f / 1024.0f) - mu * mu;
    float rs = rsqrtf(var + 1e-5f);
    const float4* wr = (const float4*)lw;
    const float4* br = (const float4*)lb;
    float4 wv = wr[tid], bv = br[tid];
    ushort4 o;
    o.x = f2bf((v.x - mu) * rs * wv.x + bv.x);
    o.y = f2bf((v.y - mu) * rs * wv.y + bv.y);
    o.z = f2bf((v.z - mu) * rs * wv.z + bv.z);
    o.w = f2bf((v.w - mu) * rs * wv.w + bv.w);
    *(ushort4*)&xn[(size_t)row * 1024 + tid * 4] = o;
}

// ---------------------------------------------------------------------------
// Kernel 3: MFMA GEMM  C[M][N] = A[M][K] @ Bt[N][K]^T, bf16 in, OutT out.
// 128x128 block tile, 4 waves (2x2), each 64x64 = 4x4 mfma_16x16x32_bf16.
// ---------------------------------------------------------------------------
template <typename OutT>
__global__ __launch_bounds__(256) void gemm_bt(const ushort* __restrict__ A,
                                               const ushort* __restrict__ Bt,
                                               OutT* __restrict__ C,
                                               int M, int N, int K) {
    __shared__ ushort As[128 * 40];
    __shared__ ushort Bs[128 * 40];
    const int tid = threadIdx.x;
    const int wave = tid >> 6, lane = tid & 63;
    const int quad = lane >> 4, l15 = lane & 15;
    const int wm = (wave >> 1) * 64, wn = (wave & 1) * 64;
    const int bm = blockIdx.y * 128, bn = blockIdx.x * 128;

    const int s0 = tid, s1 = tid + 256;
    const int row0 = s0 >> 2, seg0 = s0 & 3;
    const int row1 = s1 >> 2, seg1 = s1 & 3;

    floatx4 acc[4][4];
    floatx4 z4 = {0.f, 0.f, 0.f, 0.f};
    for (int mi = 0; mi < 4; mi++)
        for (int ni = 0; ni < 4; ni++) acc[mi][ni] = z4;

    const ushort* Ap0 = A + (size_t)(bm + row0) * K + seg0 * 8;
    const ushort* Ap1 = A + (size_t)(bm + row1) * K + seg1 * 8;
    const ushort* Bp0 = Bt + (size_t)(bn + row0) * K + seg0 * 8;
    const ushort* Bp1 = Bt + (size_t)(bn + row1) * K + seg1 * 8;

    for (int k0 = 0; k0 < K; k0 += 32) {
        __syncthreads();
        *(short8*)&As[row0 * 40 + seg0 * 8] = *(const short8*)&Ap0[k0];
        *(short8*)&As[row1 * 40 + seg1 * 8] = *(const short8*)&Ap1[k0];
        *(short8*)&Bs[row0 * 40 + seg0 * 8] = *(const short8*)&Bp0[k0];
        *(short8*)&Bs[row1 * 40 + seg1 * 8] = *(const short8*)&Bp1[k0];
        __syncthreads();
        short8 af[4], bfr[4];
        for (int mi = 0; mi < 4; mi++)
            af[mi] = *(short8*)&As[(wm + mi * 16 + l15) * 40 + quad * 8];
        for (int ni = 0; ni < 4; ni++)
            bfr[ni] = *(short8*)&Bs[(wn + ni * 16 + l15) * 40 + quad * 8];
        for (int mi = 0; mi < 4; mi++)
            for (int ni = 0; ni < 4; ni++)
                acc[mi][ni] = __builtin_amdgcn_mfma_f32_16x16x32_bf16(
                    af[mi], bfr[ni], acc[mi][ni], 0, 0, 0);
    }
    for (int mi = 0; mi < 4; mi++) {
        for (int ni = 0; ni < 4; ni++) {
            for (int r = 0; r < 4; r++) {
                int row = bm + wm + mi * 16 + quad * 4 + r;
                int col = bn + wn + ni * 16 + l15;
                float val = acc[mi][ni][r];
                if constexpr (sizeof(OutT) == 2)
                    ((ushort*)C)[(size_t)row * N + col] = f2bf(val);
                else
                    ((float*)C)[(size_t)row * N + col] = val;
            }
        }
    }
}

// ---------------------------------------------------------------------------
// Kernel 4: reshape to heads + l2-normalize q,k + transpose v.
// ---------------------------------------------------------------------------
__global__ __launch_bounds__(256) void norm_reshape(const ushort* __restrict__ qkv,
                                                    ushort* __restrict__ Q,
                                                    ushort* __restrict__ K,
                                                    ushort* __restrict__ Vt) {
    int nb = blockIdx.x;   // n-tile of 64
    int h = blockIdx.y;
    int b = blockIdx.z;
    int bh = b * 16 + h;
    int tid = threadIdx.x, wave = tid >> 6, lane = tid & 63;
    __shared__ ushort vt[64][65];  // [d][n_loc]

    for (int i = 0; i < 16; i++) {
        int idx = tid + i * 256;
        int n_loc = idx >> 6, d = idx & 63;
        size_t g = ((size_t)(b * 2048 + nb * 64 + n_loc)) * 3072 + 2048 + h * 64 + d;
        vt[d][n_loc] = qkv[g];
    }
    __syncthreads();
    for (int i = 0; i < 16; i++) {
        int idx = tid + i * 256;
        int d = idx >> 6, n_loc = idx & 63;
        Vt[((size_t)bh * 64 + d) * 2048 + nb * 64 + n_loc] = vt[d][n_loc];
    }

    for (int j = 0; j < 16; j++) {
        int n_loc = wave * 16 + j;
        size_t grow = (size_t)(b * 2048 + nb * 64 + n_loc) * 3072;
        size_t orow = ((size_t)bh * 2048 + nb * 64 + n_loc) * 64;

        float qv = bf2f(qkv[grow + h * 64 + lane]);
        float ss = qv * qv;
        for (int off = 32; off; off >>= 1) ss += __shfl_xor(ss, off);
        float inv = 1.0f / fmaxf(sqrtf(ss), 1e-12f);
        Q[orow + lane] = f2bf(qv * inv);

        float kv = bf2f(qkv[grow + 1024 + h * 64 + lane]);
        ss = kv * kv;
        for (int off = 32; off; off >>= 1) ss += __shfl_xor(ss, off);
        inv = 1.0f / fmaxf(sqrtf(ss), 1e-12f);
        K[orow + lane] = f2bf(kv * inv);
    }
}

// ---------------------------------------------------------------------------
// Kernel 5: causal flash attention, BALANCED + FIXED-MAX softmax.
// Scores are bounded: sim = 8*(q̂·k̂) ∈ [-8,8] -> no online max needed.
// p = exp(sim - 8) = exp2(11.5416*s - 11.5416), row-sum deferred to epilogue.
// Block pair: blockIdx.x=i handles qt=i then qt=31-i -> 33 k-tiles each.
// ---------------------------------------------------------------------------
#define BH_STRIDE (2048 * 64)
#define LOG2E8 11.541560327111707f   // 8 * log2(e)

__global__ __launch_bounds__(256) void flash_attn(const ushort* __restrict__ Q,
                                                  const ushort* __restrict__ K,
                                                  const ushort* __restrict__ Vt,
                                                  ushort* __restrict__ O) {
    const int pairi = blockIdx.x;  // 0..15
    const int h = blockIdx.y;
    const int b = blockIdx.z;
    const int bh = b * 16 + h;
    const int tid = threadIdx.x;
    const int wave = tid >> 6, lane = tid & 63;
    const int quad = lane >> 4, l15 = lane & 15;

    __shared__ ushort Qs[64 * 72];
    __shared__ ushort Ks[64 * 72];
    __shared__ ushort Vs[64 * 72];      // Vt tile: [d][kv]
    __shared__ ushort Ps[4][16 * 72];   // per-wave P staging

    const ushort* Kg = K + (size_t)bh * BH_STRIDE;
    const ushort* Vg = Vt + (size_t)bh * BH_STRIDE;

    for (int pass = 0; pass < 2; pass++) {
        const int qt = pass ? (31 - pairi) : pairi;
        const int q0 = qt * 64;
        const ushort* Qg = Q + (size_t)bh * BH_STRIDE + (size_t)q0 * 64;

        __syncthreads();  // protect Qs/Ks/Vs reuse across passes
        for (int i = 0; i < 2; i++) {
            int s = tid + i * 256;
            int row = s >> 3, seg = s & 7;
            *(short8*)&Qs[row * 72 + seg * 8] = *(const short8*)&Qg[row * 64 + seg * 8];
        }
        __syncthreads();
        short8 qf[2];
        qf[0] = *(short8*)&Qs[(wave * 16 + l15) * 72 + quad * 8];
        qf[1] = *(short8*)&Qs[(wave * 16 + l15) * 72 + 32 + quad * 8];

        float rs_acc[4] = {0.f, 0.f, 0.f, 0.f};
        floatx4 o_acc[4];
        floatx4 z4 = {0.f, 0.f, 0.f, 0.f};
        for (int ni = 0; ni < 4; ni++) o_acc[ni] = z4;

        for (int kt = 0; kt <= qt; kt++) {
            int kv0 = kt * 64;
            __syncthreads();  // prior iter's Ks/Vs reads complete
            for (int i = 0; i < 2; i++) {
                int s = tid + i * 256;
                int row = s >> 3, seg = s & 7;
                *(short8*)&Ks[row * 72 + seg * 8] =
                    *(const short8*)&Kg[(size_t)(kv0 + row) * 64 + seg * 8];
                *(short8*)&Vs[row * 72 + seg * 8] =
                    *(const short8*)&Vg[(size_t)row * 2048 + kv0 + seg * 8];
            }
            __syncthreads();

            floatx4 s_acc[4];
            for (int ni = 0; ni < 4; ni++) s_acc[ni] = z4;
            for (int ni = 0; ni < 4; ni++) {
                short8 bf0 = *(short8*)&Ks[(ni * 16 + l15) * 72 + quad * 8];
                short8 bf1 = *(short8*)&Ks[(ni * 16 + l15) * 72 + 32 + quad * 8];
                s_acc[ni] = __builtin_amdgcn_mfma_f32_16x16x32_bf16(qf[0], bf0, s_acc[ni], 0, 0, 0);
                s_acc[ni] = __builtin_amdgcn_mfma_f32_16x16x32_bf16(qf[1], bf1, s_acc[ni], 0, 0, 0);
            }

            // fixed-max softmax: p = exp2(11.5416*s - 11.5416) in (0,1]
            if (kt == qt) {
                for (int ni = 0; ni < 4; ni++) {
                    int col_loc = ni * 16 + l15;
                    for (int r = 0; r < 4; r++) {
                        int row_loc = wave * 16 + quad * 4 + r;
                        float e = exp2f(fmaf(s_acc[ni][r], LOG2E8, -LOG2E8));
                        e = (col_loc > row_loc) ? 0.f : e;
                        rs_acc[r] += e;
                        Ps[wave][(quad * 4 + r) * 72 + col_loc] = f2bf(e);
                    }
                }
            } else {
                for (int ni = 0; ni < 4; ni++) {
                    int col_loc = ni * 16 + l15;
                    for (int r = 0; r < 4; r++) {
                        float e = exp2f(fmaf(s_acc[ni][r], LOG2E8, -LOG2E8));
                        rs_acc[r] += e;
                        Ps[wave][(quad * 4 + r) * 72 + col_loc] = f2bf(e);
                    }
                }
            }

            // P (same-wave LDS roundtrip) -> A-layout, then PV
            short8 pa0 = *(short8*)&Ps[wave][l15 * 72 + quad * 8];
            short8 pa1 = *(short8*)&Ps[wave][l15 * 72 + 32 + quad * 8];
            for (int ni = 0; ni < 4; ni++) {
                short8 v0 = *(short8*)&Vs[(ni * 16 + l15) * 72 + quad * 8];
                short8 v1 = *(short8*)&Vs[(ni * 16 + l15) * 72 + 32 + quad * 8];
                o_acc[ni] = __builtin_amdgcn_mfma_f32_16x16x32_bf16(pa0, v0, o_acc[ni], 0, 0, 0);
                o_acc[ni] = __builtin_amdgcn_mfma_f32_16x16x32_bf16(pa1, v1, o_acc[ni], 0, 0, 0);
            }
        }

        // epilogue: single deferred row-sum reduce, then O/l
        for (int r = 0; r < 4; r++) {
            float rs = rs_acc[r];
            for (int off = 1; off < 16; off <<= 1) rs += __shfl_xor(rs, off);
            float inv = 1.0f / rs;
            int grow = q0 + wave * 16 + quad * 4 + r;
            size_t rowbase = ((size_t)b * 2048 + grow) * 1024 + h * 64;
            for (int ni = 0; ni < 4; ni++)
                O[rowbase + ni * 16 + l15] = f2bf(o_acc[ni][r] * inv);
        }
    }
}

// ---------------------------------------------------------------------------
extern "C" void kernel_launch(void* const* d_in, const int* in_sizes, int n_in,
                              void* d_out, int out_size, void* d_ws, size_t ws_size,
                              hipStream_t stream) {
    const float* x = (const float*)d_in[0];
    const float* ln_w = (const float*)d_in[1];
    const float* ln_b = (const float*)d_in[2];
    const float* W_qkv = (const float*)d_in[3];
    const float* W_out = (const float*)d_in[4];

    char* w = (char*)d_ws;
    ushort* xn    = (ushort*)(w);                          // 8 MiB
    ushort* WqkvT = (ushort*)(w + (8ull << 20));           // 6 MiB
    ushort* WoutT = (ushort*)(w + (14ull << 20));          // 2 MiB
    ushort* qkv   = (ushort*)(w + (16ull << 20));          // 24 MiB
    ushort* Qn    = (ushort*)(w + (40ull << 20));          // 8 MiB
    ushort* Kn    = (ushort*)(w + (48ull << 20));          // 8 MiB
    ushort* Vt    = (ushort*)(w + (56ull << 20));          // 8 MiB
    ushort* obuf  = (ushort*)(w + (64ull << 20));          // 8 MiB -> 72 MiB total

    transpose_cast<<<dim3(96, 32), dim3(32, 8), 0, stream>>>(W_qkv, WqkvT, 1024, 3072);
    transpose_cast<<<dim3(32, 32), dim3(32, 8), 0, stream>>>(W_out, WoutT, 1024, 1024);
    ln_kernel<<<4096, 256, 0, stream>>>(x, ln_w, ln_b, xn);
    gemm_bt<ushort><<<dim3(24, 32), 256, 0, stream>>>(xn, WqkvT, qkv, 4096, 3072, 1024);
    norm_reshape<<<dim3(32, 16, 2), 256, 0, stream>>>(qkv, Qn, Kn, Vt);
    flash_attn<<<dim3(16, 16, 2), 256, 0, stream>>>(Qn, Kn, Vt, obuf);
    gemm_bt<float><<<dim3(8, 32), 256, 0, stream>>>(obuf, WoutT, (float*)d_out, 4096, 1024, 1024);
}

// Round 3
// 212.550 us; speedup vs baseline: 1.5456x; 1.0703x over previous
//
#include <hip/hip_runtime.h>
#include <hip/hip_bf16.h>

typedef __attribute__((ext_vector_type(8))) short short8;
typedef __attribute__((ext_vector_type(4))) float floatx4;

__device__ __forceinline__ ushort f2bf(float f) {
    union { __hip_bfloat16 h; ushort u; } cv;
    cv.h = __float2bfloat16(f);
    return cv.u;
}
__device__ __forceinline__ float bf2f(ushort u) {
    union { ushort u; __hip_bfloat16 h; } cv;
    cv.u = u;
    return __bfloat162float(cv.h);
}

typedef __attribute__((address_space(1))) void* gas1_t;
typedef __attribute__((address_space(3))) void* las3_t;
// async global->LDS, 16B per lane. LDS dest = wave-uniform base + lane*16.
__device__ __forceinline__ void cp16(const ushort* g, ushort* l) {
    __builtin_amdgcn_global_load_lds((gas1_t)(unsigned long long)g,
                                     (las3_t)(unsigned long long)l, 16, 0, 0);
}

// ---------------------------------------------------------------------------
// Kernel 1: cast + transpose weights fp32[R][C] -> bf16[C][R]
// ---------------------------------------------------------------------------
__global__ __launch_bounds__(256) void transpose_cast(const float* __restrict__ in,
                                                      ushort* __restrict__ out,
                                                      int R, int C) {
    __shared__ float tile[32][33];
    int c0 = blockIdx.x * 32, r0 = blockIdx.y * 32;
    int tx = threadIdx.x, ty = threadIdx.y;
    for (int j = 0; j < 32; j += 8)
        tile[ty + j][tx] = in[(size_t)(r0 + ty + j) * C + c0 + tx];
    __syncthreads();
    for (int j = 0; j < 32; j += 8)
        out[(size_t)(c0 + ty + j) * R + r0 + tx] = f2bf(tile[tx][ty + j]);
}

// ---------------------------------------------------------------------------
// Kernel 2: LayerNorm (fp32) -> bf16. One block per row of 1024.
// ---------------------------------------------------------------------------
__global__ __launch_bounds__(256) void ln_kernel(const float* __restrict__ x,
                                                 const float* __restrict__ lw,
                                                 const float* __restrict__ lb,
                                                 ushort* __restrict__ xn) {
    int row = blockIdx.x;
    int tid = threadIdx.x;
    const float4* xr = (const float4*)(x + (size_t)row * 1024);
    float4 v = xr[tid];
    float s = v.x + v.y + v.z + v.w;
    float sq = v.x * v.x + v.y * v.y + v.z * v.z + v.w * v.w;
    for (int off = 32; off; off >>= 1) {
        s += __shfl_xor(s, off);
        sq += __shfl_xor(sq, off);
    }
    __shared__ float ls[4], lq[4];
    int wave = tid >> 6, lane = tid & 63;
    if (lane == 0) { ls[wave] = s; lq[wave] = sq; }
    __syncthreads();
    s = ls[0] + ls[1] + ls[2] + ls[3];
    sq = lq[0] + lq[1] + lq[2] + lq[3];
    float mu = s * (1.0f / 1024.0f);
    float var = sq * (1.0f / 1024.0f) - mu * mu;
    float rs = rsqrtf(var + 1e-5f);
    const float4* wr = (const float4*)lw;
    const float4* br = (const float4*)lb;
    float4 wv = wr[tid], bv = br[tid];
    ushort4 o;
    o.x = f2bf((v.x - mu) * rs * wv.x + bv.x);
    o.y = f2bf((v.y - mu) * rs * wv.y + bv.y);
    o.z = f2bf((v.z - mu) * rs * wv.z + bv.z);
    o.w = f2bf((v.w - mu) * rs * wv.w + bv.w);
    *(ushort4*)&xn[(size_t)row * 1024 + tid * 4] = o;
}

// ---------------------------------------------------------------------------
// Kernel 3: MFMA GEMM, m97-style: global_load_lds width-16 staging into
// unpadded BK=32 LDS with 16B-chunk XOR swizzle (seg ^ (row&3)) -> 4-way
// max bank conflict on ds_read_b128 fragment reads.
// C[M][N] = A[M][K] @ Bt[N][K]^T. 128x128 tile, 4 waves, 4x4 16x16x32 MFMA.
// ---------------------------------------------------------------------------
template <typename OutT>
__global__ __launch_bounds__(256) void gemm_bt(const ushort* __restrict__ A,
                                               const ushort* __restrict__ Bt,
                                               OutT* __restrict__ C,
                                               int M, int N, int K) {
    __shared__ ushort As[128 * 32];
    __shared__ ushort Bs[128 * 32];
    const int tid = threadIdx.x;
    const int wave = tid >> 6, lane = tid & 63;
    const int quad = lane >> 4, l15 = lane & 15;
    const int wm = (wave >> 1) * 64, wn = (wave & 1) * 64;
    const int bm = blockIdx.y * 128, bn = blockIdx.x * 128;

    // staging: slot s (0..511) holds 16B; lds byte offset = s*16.
    // logical: row = s>>2, slot_seg = s&3; content = global chunk (row, slot_seg ^ (row&3))
    const int s0 = tid, s1 = tid + 256;
    const int row0 = s0 >> 2, src0 = (s0 & 3) ^ (row0 & 3);
    const int row1 = s1 >> 2, src1 = (s1 & 3) ^ (row1 & 3);

    floatx4 acc[4][4];
    floatx4 z4 = {0.f, 0.f, 0.f, 0.f};
    for (int mi = 0; mi < 4; mi++)
        for (int ni = 0; ni < 4; ni++) acc[mi][ni] = z4;

    const ushort* Ap0 = A + (size_t)(bm + row0) * K + src0 * 8;
    const ushort* Ap1 = A + (size_t)(bm + row1) * K + src1 * 8;
    const ushort* Bp0 = Bt + (size_t)(bn + row0) * K + src0 * 8;
    const ushort* Bp1 = Bt + (size_t)(bn + row1) * K + src1 * 8;

    ushort* lA0 = As + wave * 512;          // wave-uniform LDS bases
    ushort* lA1 = As + 2048 + wave * 512;
    ushort* lB0 = Bs + wave * 512;
    ushort* lB1 = Bs + 2048 + wave * 512;

    for (int k0 = 0; k0 < K; k0 += 32) {
        __syncthreads();
        cp16(Ap0 + k0, lA0);
        cp16(Ap1 + k0, lA1);
        cp16(Bp0 + k0, lB0);
        cp16(Bp1 + k0, lB1);
        __syncthreads();
        short8 af[4], bfr[4];
        for (int mi = 0; mi < 4; mi++) {
            int ra = wm + mi * 16 + l15;
            af[mi] = *(short8*)&As[ra * 32 + ((quad ^ (ra & 3)) << 3)];
        }
        for (int ni = 0; ni < 4; ni++) {
            int rb = wn + ni * 16 + l15;
            bfr[ni] = *(short8*)&Bs[rb * 32 + ((quad ^ (rb & 3)) << 3)];
        }
        for (int mi = 0; mi < 4; mi++)
            for (int ni = 0; ni < 4; ni++)
                acc[mi][ni] = __builtin_amdgcn_mfma_f32_16x16x32_bf16(
                    af[mi], bfr[ni], acc[mi][ni], 0, 0, 0);
    }
    for (int mi = 0; mi < 4; mi++) {
        for (int ni = 0; ni < 4; ni++) {
            for (int r = 0; r < 4; r++) {
                int row = bm + wm + mi * 16 + quad * 4 + r;
                int col = bn + wn + ni * 16 + l15;
                float val = acc[mi][ni][r];
                if constexpr (sizeof(OutT) == 2)
                    ((ushort*)C)[(size_t)row * N + col] = f2bf(val);
                else
                    ((float*)C)[(size_t)row * N + col] = val;
            }
        }
    }
}

// ---------------------------------------------------------------------------
// Kernel 4: reshape to heads + l2-normalize q,k + transpose v.
// ---------------------------------------------------------------------------
__global__ __launch_bounds__(256) void norm_reshape(const ushort* __restrict__ qkv,
                                                    ushort* __restrict__ Q,
                                                    ushort* __restrict__ K,
                                                    ushort* __restrict__ Vt) {
    int nb = blockIdx.x;   // n-tile of 64
    int h = blockIdx.y;
    int b = blockIdx.z;
    int bh = b * 16 + h;
    int tid = threadIdx.x, wave = tid >> 6, lane = tid & 63;
    __shared__ ushort vt[64][65];  // [d][n_loc]

    for (int i = 0; i < 16; i++) {
        int idx = tid + i * 256;
        int n_loc = idx >> 6, d = idx & 63;
        size_t g = ((size_t)(b * 2048 + nb * 64 + n_loc)) * 3072 + 2048 + h * 64 + d;
        vt[d][n_loc] = qkv[g];
    }
    __syncthreads();
    for (int i = 0; i < 16; i++) {
        int idx = tid + i * 256;
        int d = idx >> 6, n_loc = idx & 63;
        Vt[((size_t)bh * 64 + d) * 2048 + nb * 64 + n_loc] = vt[d][n_loc];
    }

    for (int j = 0; j < 16; j++) {
        int n_loc = wave * 16 + j;
        size_t grow = (size_t)(b * 2048 + nb * 64 + n_loc) * 3072;
        size_t orow = ((size_t)bh * 2048 + nb * 64 + n_loc) * 64;

        float qv = bf2f(qkv[grow + h * 64 + lane]);
        float ss = qv * qv;
        for (int off = 32; off; off >>= 1) ss += __shfl_xor(ss, off);
        float inv = 1.0f / fmaxf(sqrtf(ss), 1e-12f);
        Q[orow + lane] = f2bf(qv * inv);

        float kv = bf2f(qkv[grow + 1024 + h * 64 + lane]);
        ss = kv * kv;
        for (int off = 32; off; off >>= 1) ss += __shfl_xor(ss, off);
        inv = 1.0f / fmaxf(sqrtf(ss), 1e-12f);
        K[orow + lane] = f2bf(kv * inv);
    }
}

// ---------------------------------------------------------------------------
// Kernel 5: causal flash attention v3.
// 512 threads / 8 waves; block handles two 128-row q super-tiles (st = i and
// 15-i -> 34 k-tiles/block, balanced). Each loaded K/V tile serves 128 q-rows
// (K/V traffic and barrier count halved vs 64-row tiles). Next K/V tile is
// register-prefetched right AFTER the stage-in barrier so the global loads
// are in flight during the compute section (grid = 1 block/CU -> no
// co-resident block to hide latency otherwise).
// Fixed-max softmax: sim = 8*(q̂·k̂) ∈ [-8,8] -> p = exp2(11.5416*s - 11.5416).
// ---------------------------------------------------------------------------
#define BH_STRIDE (2048 * 64)
#define LOG2E8 11.541560327111707f   // 8 * log2(e)

__global__ __launch_bounds__(512) void flash_attn(const ushort* __restrict__ Q,
                                                  const ushort* __restrict__ K,
                                                  const ushort* __restrict__ Vt,
                                                  ushort* __restrict__ O) {
    const int pairi = blockIdx.x;  // 0..7
    const int h = blockIdx.y;
    const int b = blockIdx.z;
    const int bh = b * 16 + h;
    const int tid = threadIdx.x;
    const int wave = tid >> 6, lane = tid & 63;
    const int quad = lane >> 4, l15 = lane & 15;

    __shared__ ushort Qs[128 * 72];
    __shared__ ushort Ks[64 * 72];
    __shared__ ushort Vs[64 * 72];      // Vt tile: [d][kv]
    __shared__ ushort Ps[8][16 * 72];   // per-wave P staging

    const ushort* Kg = K + (size_t)bh * BH_STRIDE;
    const ushort* Vg = Vt + (size_t)bh * BH_STRIDE;

    const int srow = tid >> 3, sseg = tid & 7;  // 512 thr cover 64 rows x 8 chunks
    const ushort* kp = Kg + (size_t)srow * 64 + sseg * 8;
    const ushort* vp = Vg + (size_t)srow * 2048 + sseg * 8;
    ushort* ksl = &Ks[srow * 72 + sseg * 8];
    ushort* vsl = &Vs[srow * 72 + sseg * 8];

    for (int pass = 0; pass < 2; pass++) {
        const int st = pass ? (15 - pairi) : pairi;
        const int q0 = st * 128;
        const int ktmax = 2 * st + 1;
        const ushort* Qg = Q + (size_t)bh * BH_STRIDE + (size_t)q0 * 64;

        __syncthreads();  // previous pass's LDS readers done
        for (int i = 0; i < 2; i++) {
            int s = tid + i * 512;
            int row = s >> 3, seg = s & 7;
            *(short8*)&Qs[row * 72 + seg * 8] = *(const short8*)&Qg[(size_t)row * 64 + seg * 8];
        }
        short8 kreg = *(const short8*)kp;    // prefetch kt=0
        short8 vreg = *(const short8*)vp;
        __syncthreads();
        short8 qf0 = *(short8*)&Qs[(wave * 16 + l15) * 72 + quad * 8];
        short8 qf1 = *(short8*)&Qs[(wave * 16 + l15) * 72 + 32 + quad * 8];

        float rs_acc[4] = {0.f, 0.f, 0.f, 0.f};
        floatx4 o_acc[4];
        floatx4 z4 = {0.f, 0.f, 0.f, 0.f};
        for (int ni = 0; ni < 4; ni++) o_acc[ni] = z4;
        const int wrow_min = q0 + wave * 16;
        const int wrow_max = wrow_min + 15;

        for (int kt = 0; kt <= ktmax; kt++) {
            const int kv0 = kt * 64;
            __syncthreads();                 // prior iter's Ks/Vs reads complete
            *(short8*)ksl = kreg;
            *(short8*)vsl = vreg;
            __syncthreads();                 // tile visible
            if (kt < ktmax) {                // prefetch next tile during compute
                kreg = *(const short8*)&kp[(size_t)(kt + 1) * 4096];
                vreg = *(const short8*)&vp[(size_t)(kt + 1) * 64];
            }
            if (kv0 > wrow_max) continue;    // fully masked for this wave

            floatx4 s_acc[4];
            for (int ni = 0; ni < 4; ni++) s_acc[ni] = z4;
            for (int ni = 0; ni < 4; ni++) {
                short8 bf0 = *(short8*)&Ks[(ni * 16 + l15) * 72 + quad * 8];
                short8 bf1 = *(short8*)&Ks[(ni * 16 + l15) * 72 + 32 + quad * 8];
                s_acc[ni] = __builtin_amdgcn_mfma_f32_16x16x32_bf16(qf0, bf0, s_acc[ni], 0, 0, 0);
                s_acc[ni] = __builtin_amdgcn_mfma_f32_16x16x32_bf16(qf1, bf1, s_acc[ni], 0, 0, 0);
            }

            if (kv0 + 63 > wrow_min) {  // diagonal tile for this wave
                for (int ni = 0; ni < 4; ni++) {
                    int col = kv0 + ni * 16 + l15;
                    for (int r = 0; r < 4; r++) {
                        int row = wrow_min + quad * 4 + r;
                        float e = exp2f(fmaf(s_acc[ni][r], LOG2E8, -LOG2E8));
                        e = (col > row) ? 0.f : e;
                        rs_acc[r] += e;
                        Ps[wave][(quad * 4 + r) * 72 + ni * 16 + l15] = f2bf(e);
                    }
                }
            } else {
                for (int ni = 0; ni < 4; ni++) {
                    for (int r = 0; r < 4; r++) {
                        float e = exp2f(fmaf(s_acc[ni][r], LOG2E8, -LOG2E8));
                        rs_acc[r] += e;
                        Ps[wave][(quad * 4 + r) * 72 + ni * 16 + l15] = f2bf(e);
                    }
                }
            }

            short8 pa0 = *(short8*)&Ps[wave][l15 * 72 + quad * 8];
            short8 pa1 = *(short8*)&Ps[wave][l15 * 72 + 32 + quad * 8];
            for (int ni = 0; ni < 4; ni++) {
                short8 v0 = *(short8*)&Vs[(ni * 16 + l15) * 72 + quad * 8];
                short8 v1 = *(short8*)&Vs[(ni * 16 + l15) * 72 + 32 + quad * 8];
                o_acc[ni] = __builtin_amdgcn_mfma_f32_16x16x32_bf16(pa0, v0, o_acc[ni], 0, 0, 0);
                o_acc[ni] = __builtin_amdgcn_mfma_f32_16x16x32_bf16(pa1, v1, o_acc[ni], 0, 0, 0);
            }
        }

        // epilogue: deferred row-sum reduce, then O/l
        for (int r = 0; r < 4; r++) {
            float rs = rs_acc[r];
            for (int off = 1; off < 16; off <<= 1) rs += __shfl_xor(rs, off);
            float inv = 1.0f / rs;
            int grow = q0 + wave * 16 + quad * 4 + r;
            size_t rowbase = ((size_t)b * 2048 + grow) * 1024 + h * 64;
            for (int ni = 0; ni < 4; ni++)
                O[rowbase + ni * 16 + l15] = f2bf(o_acc[ni][r] * inv);
        }
    }
}

// ---------------------------------------------------------------------------
extern "C" void kernel_launch(void* const* d_in, const int* in_sizes, int n_in,
                              void* d_out, int out_size, void* d_ws, size_t ws_size,
                              hipStream_t stream) {
    const float* x = (const float*)d_in[0];
    const float* ln_w = (const float*)d_in[1];
    const float* ln_b = (const float*)d_in[2];
    const float* W_qkv = (const float*)d_in[3];
    const float* W_out = (const float*)d_in[4];

    char* w = (char*)d_ws;
    ushort* xn    = (ushort*)(w);                          // 8 MiB
    ushort* WqkvT = (ushort*)(w + (8ull << 20));           // 6 MiB
    ushort* WoutT = (ushort*)(w + (14ull << 20));          // 2 MiB
    ushort* qkv   = (ushort*)(w + (16ull << 20));          // 24 MiB
    ushort* Qn    = (ushort*)(w + (40ull << 20));          // 8 MiB
    ushort* Kn    = (ushort*)(w + (48ull << 20));          // 8 MiB
    ushort* Vt    = (ushort*)(w + (56ull << 20));          // 8 MiB
    ushort* obuf  = (ushort*)(w + (64ull << 20));          // 8 MiB -> 72 MiB total

    transpose_cast<<<dim3(96, 32), dim3(32, 8), 0, stream>>>(W_qkv, WqkvT, 1024, 3072);
    transpose_cast<<<dim3(32, 32), dim3(32, 8), 0, stream>>>(W_out, WoutT, 1024, 1024);
    ln_kernel<<<4096, 256, 0, stream>>>(x, ln_w, ln_b, xn);
    gemm_bt<ushort><<<dim3(24, 32), 256, 0, stream>>>(xn, WqkvT, qkv, 4096, 3072, 1024);
    norm_reshape<<<dim3(32, 16, 2), 256, 0, stream>>>(qkv, Qn, Kn, Vt);
    flash_attn<<<dim3(8, 16, 2), 512, 0, stream>>>(Qn, Kn, Vt, obuf);
    gemm_bt<float><<<dim3(8, 32), 256, 0, stream>>>(obuf, WoutT, (float*)d_out, 4096, 1024, 1024);
}

// Round 4
// 207.826 us; speedup vs baseline: 1.5808x; 1.0227x over previous
//
#include <hip/hip_runtime.h>
#include <hip/hip_bf16.h>

typedef __attribute__((ext_vector_type(8))) short short8;
typedef __attribute__((ext_vector_type(4))) float floatx4;

__device__ __forceinline__ ushort f2bf(float f) {
    union { __hip_bfloat16 h; ushort u; } cv;
    cv.h = __float2bfloat16(f);
    return cv.u;
}
__device__ __forceinline__ float bf2f(ushort u) {
    union { ushort u; __hip_bfloat16 h; } cv;
    cv.u = u;
    return __bfloat162float(cv.h);
}
// truncating f32->bf16 (RTZ): 1 shr. Used for P only (bias cancels in softmax ratio).
__device__ __forceinline__ ushort f2bf_rtz(float f) {
    union { float f; unsigned u; } cv;
    cv.f = f;
    return (ushort)(cv.u >> 16);
}

typedef __attribute__((address_space(1))) void* gas1_t;
typedef __attribute__((address_space(3))) void* las3_t;
// async global->LDS, 16B per lane. LDS dest = wave-uniform base + lane*16.
__device__ __forceinline__ void cp16(const ushort* g, ushort* l) {
    __builtin_amdgcn_global_load_lds((gas1_t)(unsigned long long)g,
                                     (las3_t)(unsigned long long)l, 16, 0, 0);
}

// ---------------------------------------------------------------------------
// Kernel 1: cast + transpose weights fp32[R][C] -> bf16[C][R]
// ---------------------------------------------------------------------------
__global__ __launch_bounds__(256) void transpose_cast(const float* __restrict__ in,
                                                      ushort* __restrict__ out,
                                                      int R, int C) {
    __shared__ float tile[32][33];
    int c0 = blockIdx.x * 32, r0 = blockIdx.y * 32;
    int tx = threadIdx.x, ty = threadIdx.y;
    for (int j = 0; j < 32; j += 8)
        tile[ty + j][tx] = in[(size_t)(r0 + ty + j) * C + c0 + tx];
    __syncthreads();
    for (int j = 0; j < 32; j += 8)
        out[(size_t)(c0 + ty + j) * R + r0 + tx] = f2bf(tile[tx][ty + j]);
}

// ---------------------------------------------------------------------------
// Kernel 2: LayerNorm (fp32) -> bf16. One block per row of 1024.
// ---------------------------------------------------------------------------
__global__ __launch_bounds__(256) void ln_kernel(const float* __restrict__ x,
                                                 const float* __restrict__ lw,
                                                 const float* __restrict__ lb,
                                                 ushort* __restrict__ xn) {
    int row = blockIdx.x;
    int tid = threadIdx.x;
    const float4* xr = (const float4*)(x + (size_t)row * 1024);
    float4 v = xr[tid];
    float s = v.x + v.y + v.z + v.w;
    float sq = v.x * v.x + v.y * v.y + v.z * v.z + v.w * v.w;
    for (int off = 32; off; off >>= 1) {
        s += __shfl_xor(s, off);
        sq += __shfl_xor(sq, off);
    }
    __shared__ float ls[4], lq[4];
    int wave = tid >> 6, lane = tid & 63;
    if (lane == 0) { ls[wave] = s; lq[wave] = sq; }
    __syncthreads();
    s = ls[0] + ls[1] + ls[2] + ls[3];
    sq = lq[0] + lq[1] + lq[2] + lq[3];
    float mu = s * (1.0f / 1024.0f);
    float var = sq * (1.0f / 1024.0f) - mu * mu;
    float rs = rsqrtf(var + 1e-5f);
    const float4* wr = (const float4*)lw;
    const float4* br = (const float4*)lb;
    float4 wv = wr[tid], bv = br[tid];
    ushort4 o;
    o.x = f2bf((v.x - mu) * rs * wv.x + bv.x);
    o.y = f2bf((v.y - mu) * rs * wv.y + bv.y);
    o.z = f2bf((v.z - mu) * rs * wv.z + bv.z);
    o.w = f2bf((v.w - mu) * rs * wv.w + bv.w);
    *(ushort4*)&xn[(size_t)row * 1024 + tid * 4] = o;
}

// ---------------------------------------------------------------------------
// Kernel 3: MFMA GEMM with single-barrier double-buffered K-loop:
//   sync -> issue cp16(t+1) into other buffer -> compute tile t.
// The vmcnt(0) drain at the next barrier lands after a full compute section,
// so the prefetch is in flight during MFMA (the m97 barrier-drain fix).
// C[M][N] = A[M][K] @ Bt[N][K]^T. 128x128 tile, 4 waves, 4x4 16x16x32 MFMA.
// LDS: unpadded BK=32, 16B-chunk XOR swizzle (slot = seg ^ (row&3)).
// ---------------------------------------------------------------------------
template <typename OutT>
__global__ __launch_bounds__(256) void gemm_bt(const ushort* __restrict__ A,
                                               const ushort* __restrict__ Bt,
                                               OutT* __restrict__ C,
                                               int M, int N, int K) {
    __shared__ ushort As[2][128 * 32];
    __shared__ ushort Bs[2][128 * 32];
    const int tid = threadIdx.x;
    const int wave = tid >> 6, lane = tid & 63;
    const int quad = lane >> 4, l15 = lane & 15;
    const int wm = (wave >> 1) * 64, wn = (wave & 1) * 64;
    const int bm = blockIdx.y * 128, bn = blockIdx.x * 128;

    const int s0 = tid, s1 = tid + 256;
    const int row0 = s0 >> 2, src0 = (s0 & 3) ^ (row0 & 3);
    const int row1 = s1 >> 2, src1 = (s1 & 3) ^ (row1 & 3);

    floatx4 acc[4][4];
    floatx4 z4 = {0.f, 0.f, 0.f, 0.f};
    for (int mi = 0; mi < 4; mi++)
        for (int ni = 0; ni < 4; ni++) acc[mi][ni] = z4;

    const ushort* Ap0 = A + (size_t)(bm + row0) * K + src0 * 8;
    const ushort* Ap1 = A + (size_t)(bm + row1) * K + src1 * 8;
    const ushort* Bp0 = Bt + (size_t)(bn + row0) * K + src0 * 8;
    const ushort* Bp1 = Bt + (size_t)(bn + row1) * K + src1 * 8;

    const int T = K >> 5;
    // pre-issue tile 0 into buffer 0
    cp16(Ap0, &As[0][wave * 512]);
    cp16(Ap1, &As[0][2048 + wave * 512]);
    cp16(Bp0, &Bs[0][wave * 512]);
    cp16(Bp1, &Bs[0][2048 + wave * 512]);

    for (int t = 0; t < T; t++) {
        __syncthreads();               // drains cp16(t) -> tile t published
        if (t + 1 < T) {               // prefetch t+1 during compute of t
            const int nb = (t + 1) & 1;
            const int k0n = (t + 1) << 5;
            cp16(Ap0 + k0n, &As[nb][wave * 512]);
            cp16(Ap1 + k0n, &As[nb][2048 + wave * 512]);
            cp16(Bp0 + k0n, &Bs[nb][wave * 512]);
            cp16(Bp1 + k0n, &Bs[nb][2048 + wave * 512]);
        }
        const ushort* Ab = As[t & 1];
        const ushort* Bb = Bs[t & 1];
        short8 af[4], bfr[4];
        for (int mi = 0; mi < 4; mi++) {
            int ra = wm + mi * 16 + l15;
            af[mi] = *(const short8*)&Ab[ra * 32 + ((quad ^ (ra & 3)) << 3)];
        }
        for (int ni = 0; ni < 4; ni++) {
            int rb = wn + ni * 16 + l15;
            bfr[ni] = *(const short8*)&Bb[rb * 32 + ((quad ^ (rb & 3)) << 3)];
        }
        for (int mi = 0; mi < 4; mi++)
            for (int ni = 0; ni < 4; ni++)
                acc[mi][ni] = __builtin_amdgcn_mfma_f32_16x16x32_bf16(
                    af[mi], bfr[ni], acc[mi][ni], 0, 0, 0);
    }
    for (int mi = 0; mi < 4; mi++) {
        for (int ni = 0; ni < 4; ni++) {
            for (int r = 0; r < 4; r++) {
                int row = bm + wm + mi * 16 + quad * 4 + r;
                int col = bn + wn + ni * 16 + l15;
                float val = acc[mi][ni][r];
                if constexpr (sizeof(OutT) == 2)
                    ((ushort*)C)[(size_t)row * N + col] = f2bf(val);
                else
                    ((float*)C)[(size_t)row * N + col] = val;
            }
        }
    }
}

// ---------------------------------------------------------------------------
// Kernel 4: prep — V transpose (qkv -> Vt[bh][d][n]) + q/k inverse row norms.
// No normalized Q/K materialization: norms folded into flash softmax.
// ---------------------------------------------------------------------------
__global__ __launch_bounds__(256) void prep(const ushort* __restrict__ qkv,
                                            ushort* __restrict__ Vt,
                                            float* __restrict__ qn,
                                            float* __restrict__ kn) {
    const int nb = blockIdx.x;   // n-tile of 64
    const int h = blockIdx.y;
    const int b = blockIdx.z;
    const int bh = b * 16 + h;
    const int tid = threadIdx.x, wave = tid >> 6, lane = tid & 63;
    __shared__ ushort vt[64][72];  // [d][n_loc]

    union S8 { short8 v; ushort u[8]; };
    for (int i = 0; i < 2; i++) {
        int c = tid + i * 256;
        int nl = c >> 3, sg = c & 7;
        S8 vv;
        vv.v = *(const short8*)&qkv[(size_t)(b * 2048 + nb * 64 + nl) * 3072 + 2048 + h * 64 + sg * 8];
        for (int j = 0; j < 8; j++) vt[sg * 8 + j][nl] = vv.u[j];
    }
    __syncthreads();
    for (int i = 0; i < 2; i++) {
        int c = tid + i * 256;
        int d = c >> 3, sg = c & 7;
        *(short8*)&Vt[((size_t)bh * 64 + d) * 2048 + nb * 64 + sg * 8] =
            *(const short8*)&vt[d][sg * 8];
    }

    for (int j = 0; j < 16; j++) {
        int nl = wave * 16 + j;
        size_t rowb = (size_t)(b * 2048 + nb * 64 + nl) * 3072 + h * 64;
        float qv = bf2f(qkv[rowb + lane]);
        float ss = qv * qv;
        for (int off = 32; off; off >>= 1) ss += __shfl_xor(ss, off);
        if (lane == 0) qn[(size_t)bh * 2048 + nb * 64 + nl] = 1.0f / fmaxf(sqrtf(ss), 1e-12f);
        float kv = bf2f(qkv[rowb + 1024 + lane]);
        ss = kv * kv;
        for (int off = 32; off; off >>= 1) ss += __shfl_xor(ss, off);
        if (lane == 0) kn[(size_t)bh * 2048 + nb * 64 + nl] = 1.0f / fmaxf(sqrtf(ss), 1e-12f);
    }
}

// ---------------------------------------------------------------------------
// Kernel 5: causal flash attention v4.
// 256 thr / 4 waves, 64-row q-tile, paired (st = i, 31-i) -> 33 k-tiles/block,
// grid 512 = 2 blocks/CU co-resident. Q-frags direct from global (raw q).
// K/V double-buffered via async cp16, ONE barrier per k-tile:
//   sync -> issue cp16(t+1) -> compute(t).
// Norms folded: e = exp2((s*kn_j)*(C*qn_i) - C), C = 8*log2(e). P stored RTZ.
// ---------------------------------------------------------------------------
#define LOG2E8 11.541560327111707f   // 8 * log2(e)

__global__ __launch_bounds__(256) void flash_attn(const ushort* __restrict__ qkv,
                                                  const float* __restrict__ qn,
                                                  const float* __restrict__ kn,
                                                  const ushort* __restrict__ Vt,
                                                  ushort* __restrict__ O) {
    const int pairi = blockIdx.x;  // 0..15
    const int h = blockIdx.y;
    const int b = blockIdx.z;
    const int bh = b * 16 + h;
    const int tid = threadIdx.x;
    const int wave = tid >> 6, lane = tid & 63;
    const int quad = lane >> 4, l15 = lane & 15;

    __shared__ ushort Ks[2][64 * 64];
    __shared__ ushort Vs[2][64 * 64];
    __shared__ ushort Ps[4][16 * 72];

    // staging: 512 chunks/tile, 2 per thread. chunk ch: row=ch>>3, slot=ch&7,
    // content = global seg (slot ^ (row&7))  [8-slot XOR swizzle]
    const int ch0 = tid, ch1 = tid + 256;
    const int r0 = ch0 >> 3, sg0 = (ch0 & 7) ^ (r0 & 7);
    const int r1 = ch1 >> 3, sg1 = (ch1 & 7) ^ (r1 & 7);

    const ushort* Kp0 = qkv + (size_t)(b * 2048 + r0) * 3072 + 1024 + h * 64 + sg0 * 8;
    const ushort* Kp1 = qkv + (size_t)(b * 2048 + r1) * 3072 + 1024 + h * 64 + sg1 * 8;
    const ushort* Vp0 = Vt + ((size_t)bh * 64 + r0) * 2048 + sg0 * 8;
    const ushort* Vp1 = Vt + ((size_t)bh * 64 + r1) * 2048 + sg1 * 8;

    const float* knb = kn + (size_t)bh * 2048;
    floatx4 z4 = {0.f, 0.f, 0.f, 0.f};

    for (int pass = 0; pass < 2; pass++) {
        const int st = pass ? (31 - pairi) : pairi;
        const int q0 = st * 64;

        // Q fragments direct from global (raw, un-normalized)
        const ushort* Qp = qkv + (size_t)(b * 2048 + q0 + wave * 16 + l15) * 3072 + h * 64;
        short8 qf0 = *(const short8*)(Qp + quad * 8);
        short8 qf1 = *(const short8*)(Qp + 32 + quad * 8);
        float a_r[4];
        for (int r = 0; r < 4; r++)
            a_r[r] = LOG2E8 * qn[(size_t)bh * 2048 + q0 + wave * 16 + quad * 4 + r];

        float rs_acc[4] = {0.f, 0.f, 0.f, 0.f};
        floatx4 o_acc[4];
        for (int ni = 0; ni < 4; ni++) o_acc[ni] = z4;

        __syncthreads();  // prior pass's LDS readers done before re-staging buf0
        cp16(Kp0, &Ks[0][wave * 512]);           // pre-issue tile 0
        cp16(Kp1, &Ks[0][2048 + wave * 512]);
        cp16(Vp0, &Vs[0][wave * 512]);
        cp16(Vp1, &Vs[0][2048 + wave * 512]);

        for (int kt = 0; kt <= st; kt++) {
            const int kv0 = kt * 64;
            __syncthreads();                     // drains cp16(kt) -> published
            if (kt < st) {                       // prefetch kt+1 during compute
                const int nb2 = (kt + 1) & 1;
                const size_t ko = (size_t)(kv0 + 64) * 3072;
                cp16(Kp0 + ko, &Ks[nb2][wave * 512]);
                cp16(Kp1 + ko, &Ks[nb2][2048 + wave * 512]);
                cp16(Vp0 + kv0 + 64, &Vs[nb2][wave * 512]);
                cp16(Vp1 + kv0 + 64, &Vs[nb2][2048 + wave * 512]);
            }
            const ushort* Kb = Ks[kt & 1];
            const ushort* Vb = Vs[kt & 1];

            // S = Q K^T (raw)
            floatx4 s_acc[4];
            for (int ni = 0; ni < 4; ni++) s_acc[ni] = z4;
            for (int ni = 0; ni < 4; ni++) {
                int rb = ni * 16 + l15;
                short8 kf0 = *(const short8*)&Kb[rb * 64 + ((quad ^ (rb & 7)) << 3)];
                short8 kf1 = *(const short8*)&Kb[rb * 64 + (((quad + 4) ^ (rb & 7)) << 3)];
                s_acc[ni] = __builtin_amdgcn_mfma_f32_16x16x32_bf16(qf0, kf0, s_acc[ni], 0, 0, 0);
                s_acc[ni] = __builtin_amdgcn_mfma_f32_16x16x32_bf16(qf1, kf1, s_acc[ni], 0, 0, 0);
            }

            // softmax numerator: e = exp2((s*kn)*(C*qn) - C), fixed max (sim<=8)
            const bool diag = (kt == st);
            for (int ni = 0; ni < 4; ni++) {
                const int col_loc = ni * 16 + l15;
                const float knv = knb[kv0 + col_loc];
                for (int r = 0; r < 4; r++) {
                    float e = __builtin_amdgcn_exp2f(
                        fmaf(s_acc[ni][r] * knv, a_r[r], -LOG2E8));
                    if (diag && col_loc > wave * 16 + quad * 4 + r) e = 0.f;
                    rs_acc[r] += e;
                    Ps[wave][(quad * 4 + r) * 72 + col_loc] = f2bf_rtz(e);
                }
            }

            // P (same-wave LDS roundtrip) -> A-layout, then PV
            short8 pa0 = *(const short8*)&Ps[wave][l15 * 72 + quad * 8];
            short8 pa1 = *(const short8*)&Ps[wave][l15 * 72 + 32 + quad * 8];
            for (int ni = 0; ni < 4; ni++) {
                int rv = ni * 16 + l15;
                short8 v0 = *(const short8*)&Vb[rv * 64 + ((quad ^ (rv & 7)) << 3)];
                short8 v1 = *(const short8*)&Vb[rv * 64 + (((quad + 4) ^ (rv & 7)) << 3)];
                o_acc[ni] = __builtin_amdgcn_mfma_f32_16x16x32_bf16(pa0, v0, o_acc[ni], 0, 0, 0);
                o_acc[ni] = __builtin_amdgcn_mfma_f32_16x16x32_bf16(pa1, v1, o_acc[ni], 0, 0, 0);
            }
        }

        // epilogue: deferred row-sum reduce, then O/l -> [b, n, h*64+d]
        for (int r = 0; r < 4; r++) {
            float rs = rs_acc[r];
            for (int off = 1; off < 16; off <<= 1) rs += __shfl_xor(rs, off);
            float inv = 1.0f / rs;
            int grow = q0 + wave * 16 + quad * 4 + r;
            size_t rowbase = ((size_t)b * 2048 + grow) * 1024 + h * 64;
            for (int ni = 0; ni < 4; ni++)
                O[rowbase + ni * 16 + l15] = f2bf(o_acc[ni][r] * inv);
        }
    }
}

// ---------------------------------------------------------------------------
extern "C" void kernel_launch(void* const* d_in, const int* in_sizes, int n_in,
                              void* d_out, int out_size, void* d_ws, size_t ws_size,
                              hipStream_t stream) {
    const float* x = (const float*)d_in[0];
    const float* ln_w = (const float*)d_in[1];
    const float* ln_b = (const float*)d_in[2];
    const float* W_qkv = (const float*)d_in[3];
    const float* W_out = (const float*)d_in[4];

    char* w = (char*)d_ws;
    ushort* xn    = (ushort*)(w);                          // 8 MiB
    ushort* WqkvT = (ushort*)(w + (8ull << 20));           // 6 MiB
    ushort* WoutT = (ushort*)(w + (14ull << 20));          // 2 MiB
    ushort* qkv   = (ushort*)(w + (16ull << 20));          // 24 MiB
    ushort* Vt    = (ushort*)(w + (40ull << 20));          // 8 MiB
    float*  qn    = (float*)(w + (48ull << 20));           // 0.25 MiB
    float*  kn    = (float*)(w + (49ull << 20));           // 0.25 MiB
    ushort* obuf  = (ushort*)(w + (50ull << 20));          // 8 MiB -> 58 MiB total

    transpose_cast<<<dim3(96, 32), dim3(32, 8), 0, stream>>>(W_qkv, WqkvT, 1024, 3072);
    transpose_cast<<<dim3(32, 32), dim3(32, 8), 0, stream>>>(W_out, WoutT, 1024, 1024);
    ln_kernel<<<4096, 256, 0, stream>>>(x, ln_w, ln_b, xn);
    gemm_bt<ushort><<<dim3(24, 32), 256, 0, stream>>>(xn, WqkvT, qkv, 4096, 3072, 1024);
    prep<<<dim3(32, 16, 2), 256, 0, stream>>>(qkv, Vt, qn, kn);
    flash_attn<<<dim3(16, 16, 2), 256, 0, stream>>>(qkv, qn, kn, Vt, obuf);
    gemm_bt<float><<<dim3(8, 32), 256, 0, stream>>>(obuf, WoutT, (float*)d_out, 4096, 1024, 1024);
}